// Round 1
// baseline (1065.444 us; speedup 1.0000x reference)
//
#include <hip/hip_runtime.h>

#define TPB 256

// ---------------------------------------------------------------------------
// B=8, H=W=256, Cin=Cout=8, N=511 (=2H-1), crop offset 127.
// Half-spectrum (k2 in [0,256)) via Hermitian-symmetrized kernel Ke.
// All GEMM dims padded to 512/256 (zero rows via zeroed table entries).
// ---------------------------------------------------------------------------

// Atab [k*256+n]  = exp(-2*pi*i*k*n/511), k in [0,512), row 511 = 0
// AtabTh[w*256+k2]= exp(-2*pi*i*k2*w/511), k2 in [0,256)
// Ctab [p*512+k1] = exp(+2*pi*i*k1*(p+127)/511)/511, k1 in [0,512), col 511 = 0
// Ct2T [k2*256+q] = w(k2)*exp(+2*pi*i*k2*(q+127)/511)/511, w(0)=1 else 2
__global__ __launch_bounds__(TPB)
void build_tables_k(float2* __restrict__ Atab, float2* __restrict__ AtabTh,
                    float2* __restrict__ Ctab, float2* __restrict__ Ct2T) {
    int idx = blockIdx.x * TPB + threadIdx.x;   // [0, 131072)
    const float w = (float)(6.28318530717958647692 / 511.0);
    {
        int k = idx >> 8, n = idx & 255;
        float2 v = make_float2(0.f, 0.f);
        if (k < 511) {
            int m = (k * n) % 511;
            float s, c; sincosf(w * (float)m, &s, &c);
            v = make_float2(c, -s);
        }
        Atab[idx] = v;
        if (k < 256) AtabTh[n * 256 + k] = v;
    }
    {
        int p = idx >> 9, k1 = idx & 511;
        float2 v = make_float2(0.f, 0.f);
        if (k1 < 511) {
            int m = (k1 * (p + 127)) % 511;
            float s, c; sincosf(w * (float)m, &s, &c);
            v = make_float2(c / 511.f, s / 511.f);
        }
        Ctab[p * 512 + k1] = v;
    }
    if (idx < 65536) {
        int k2 = idx >> 8, q = idx & 255;
        int m = (k2 * (q + 127)) % 511;
        float s, c; sincosf(w * (float)m, &s, &c);
        float sc = (k2 == 0 ? 1.f : 2.f) / 511.f;
        Ct2T[idx] = make_float2(c * sc, s * sc);
    }
}

// x [b][n][w][i] -> xT [(b*8+i)][n*256+w]
__global__ __launch_bounds__(TPB)
void transpose_x_k(const float4* __restrict__ x4, float* __restrict__ xT) {
    int idx = blockIdx.x * TPB + threadIdx.x;   // 8*256*256
    if (idx >= 8 * 256 * 256) return;
    float4 v0 = x4[idx * 2];
    float4 v1 = x4[idx * 2 + 1];
    float vv[8] = {v0.x, v0.y, v0.z, v0.w, v1.x, v1.y, v1.z, v1.w};
    int b  = idx >> 16;
    int nw = idx & 65535;
    float* dst = xT + ((size_t)b << 19) + nw;
    #pragma unroll
    for (int i = 0; i < 8; i++) dst[(size_t)i * 65536] = vv[i];
}

// Hermitian-symmetrize kernel into transposed half-table planes:
//   KeR/KeI[io][k1*256+k2] for k1 in [0,511), k2 in [0,256)
//   Ke(k) = 0.5*(Kc(k) + conj(Kc(-k)))
__global__ __launch_bounds__(TPB)
void ksym_k(const float* __restrict__ Kr, const float* __restrict__ Ki,
            float* __restrict__ KeR, float* __restrict__ KeI) {
    __shared__ float LR[64][65];
    __shared__ float LI[64][65];
    const int tid = threadIdx.x;
    const int pt0 = blockIdx.x * 64;            // 2044 blocks * 64 = 130816
    #pragma unroll
    for (int t = 0; t < 4; t++) {
        int idx = tid + t * 256;
        int ptl = idx >> 4, j = idx & 15;
        int pt2 = pt0 + ptl;
        int k1 = pt2 >> 8, k2 = pt2 & 255;
        int k1m = (511 - k1) % 511;
        int k2m = (511 - k2) % 511;
        size_t so = ((size_t)(k1  * 511 + k2 )) * 64 + j * 4;
        size_t mo = ((size_t)(k1m * 511 + k2m)) * 64 + j * 4;
        float4 rs = *(const float4*)(Kr + so);
        float4 rm = *(const float4*)(Kr + mo);
        float4 is = *(const float4*)(Ki + so);
        float4 im = *(const float4*)(Ki + mo);
        LR[j * 4 + 0][ptl] = 0.5f * (rs.x + rm.x);
        LR[j * 4 + 1][ptl] = 0.5f * (rs.y + rm.y);
        LR[j * 4 + 2][ptl] = 0.5f * (rs.z + rm.z);
        LR[j * 4 + 3][ptl] = 0.5f * (rs.w + rm.w);
        LI[j * 4 + 0][ptl] = 0.5f * (is.x - im.x);
        LI[j * 4 + 1][ptl] = 0.5f * (is.y - im.y);
        LI[j * 4 + 2][ptl] = 0.5f * (is.z - im.z);
        LI[j * 4 + 3][ptl] = 0.5f * (is.w - im.w);
    }
    __syncthreads();
    #pragma unroll
    for (int t = 0; t < 32; t++) {
        int idx = tid + t * 256;
        int plane = idx >> 6, ptl = idx & 63;
        if (plane < 64) KeR[(size_t)plane * 131072 + pt0 + ptl] = LR[plane][ptl];
        else KeI[(size_t)(plane - 64) * 131072 + pt0 + ptl] = LI[plane - 64][ptl];
    }
}

// ---------------------------------------------------------------------------
// Batched complex GEMM, no bounds checks (M mult of 128; N mult of 64; K of 16).
// A complex (z-stride sAb float2). BC: B complex. DR: D=Re(.)+bias[z&7].
// Asi stored NEGATED in LDS; negations in math via free VOP3 neg modifiers.
// Tile 128x64, BK=16, 256 threads, 8x4 micro-tile, register-prefetch
// pipeline: next-tile global loads issue right after the first barrier and
// overlap the 16-kk compute phase (issue-early / LDS-write-late).
// ---------------------------------------------------------------------------
template<bool BC, bool DR>
__global__ __launch_bounds__(TPB, 2)
void cgemm_k(int K,
             const float2* __restrict__ A2, int sAm, int sAb,
             const float2* __restrict__ B2, int sBk, int sBb,
             float* __restrict__ Dv, int sDm, int sDn, int sDzHi, int sDzLo,
             const float* __restrict__ bias)
{
    __shared__ float Asr[16][132];
    __shared__ float Asi[16][132];
    __shared__ float Bsr[16][68];
    __shared__ float Bsi[16][68];

    const int tid = threadIdx.x;
    const int tx = tid & 15, ty = tid >> 4;
    const int bm = blockIdx.y * 128, bn = blockIdx.x * 64;
    const int z = blockIdx.z;

    const float2* A = A2 + (size_t)z * sAb;
    const float2* B = B2 + (size_t)z * sBb;

    const int ak  = tid & 15, am0 = tid >> 4;   // A-stage: row am0+16t, col ak
    const int bni = tid & 63, bk0 = tid >> 6;   // B-stage: row bk0+4t, col bni

    const float2* aP[8];
    const float2* bP[4];
    const float*  bPf[4];
    #pragma unroll
    for (int t = 0; t < 8; t++)
        aP[t] = A + (size_t)(bm + am0 + 16 * t) * sAm + ak;
    #pragma unroll
    for (int t = 0; t < 4; t++) {
        if constexpr (BC) bP[t]  = B + (size_t)(bk0 + 4 * t) * sBk + bn + bni;
        else              bPf[t] = (const float*)B + (size_t)(bk0 + 4 * t) * sBk + bn + bni;
    }

    // prologue: prefetch tile 0 into registers
    float2 av[8]; float2 bv[4]; float bvf[4];
    #pragma unroll
    for (int t = 0; t < 8; t++) { av[t] = *aP[t]; aP[t] += 16; }
    #pragma unroll
    for (int t = 0; t < 4; t++) {
        if constexpr (BC) { bv[t] = *bP[t]; bP[t] += (size_t)16 * sBk; }
        else { bvf[t] = *bPf[t]; bPf[t] += (size_t)16 * sBk; }
    }

    float accR[8][4] = {{0.f}}, accI[8][4] = {{0.f}};
    const int m0 = ty * 8, n0 = tx * 4;

    for (int k0 = 0; k0 < K; k0 += 16) {
        // write staged registers to LDS
        #pragma unroll
        for (int t = 0; t < 8; t++) {
            Asr[ak][am0 + 16 * t] = av[t].x;
            Asi[ak][am0 + 16 * t] = -av[t].y;   // negated imag
        }
        #pragma unroll
        for (int t = 0; t < 4; t++) {
            if constexpr (BC) {
                Bsr[bk0 + 4 * t][bni] = bv[t].x;
                Bsi[bk0 + 4 * t][bni] = bv[t].y;
            } else {
                Bsr[bk0 + 4 * t][bni] = bvf[t];
            }
        }
        __syncthreads();

        // issue next tile's global loads; they drain during the compute phase
        if (k0 + 16 < K) {
            #pragma unroll
            for (int t = 0; t < 8; t++) { av[t] = *aP[t]; aP[t] += 16; }
            #pragma unroll
            for (int t = 0; t < 4; t++) {
                if constexpr (BC) { bv[t] = *bP[t]; bP[t] += (size_t)16 * sBk; }
                else { bvf[t] = *bPf[t]; bPf[t] += (size_t)16 * sBk; }
            }
        }

        #pragma unroll
        for (int kk = 0; kk < 16; kk++) {
            float ar8[8], an8[8], br4[4], bi4[4];
            *(float4*)&ar8[0] = *(const float4*)&Asr[kk][m0];
            *(float4*)&ar8[4] = *(const float4*)&Asr[kk][m0 + 4];
            *(float4*)&an8[0] = *(const float4*)&Asi[kk][m0];
            *(float4*)&an8[4] = *(const float4*)&Asi[kk][m0 + 4];
            *(float4*)br4 = *(const float4*)&Bsr[kk][n0];
            if constexpr (BC) *(float4*)bi4 = *(const float4*)&Bsi[kk][n0];
            #pragma unroll
            for (int i = 0; i < 8; i++)
                #pragma unroll
                for (int j = 0; j < 4; j++) {
                    if constexpr (BC && !DR) {
                        accR[i][j] = fmaf(ar8[i], br4[j], accR[i][j]);
                        accR[i][j] = fmaf(an8[i], bi4[j], accR[i][j]);
                        accI[i][j] = fmaf(ar8[i], bi4[j], accI[i][j]);
                        accI[i][j] = fmaf(-an8[i], br4[j], accI[i][j]);
                    } else if constexpr (BC && DR) {
                        accR[i][j] = fmaf(ar8[i], br4[j], accR[i][j]);
                        accR[i][j] = fmaf(an8[i], bi4[j], accR[i][j]);
                    } else {
                        accR[i][j] = fmaf(ar8[i], br4[j], accR[i][j]);
                        accI[i][j] = fmaf(-an8[i], br4[j], accI[i][j]);
                    }
                }
        }
        __syncthreads();
    }

    float bz = 0.f;
    if constexpr (DR) { if (bias != nullptr) bz = bias[z & 7]; }

    const size_t dbase = (size_t)(z >> 3) * sDzHi + (size_t)(z & 7) * sDzLo;
    #pragma unroll
    for (int i = 0; i < 8; i++) {
        int gm = bm + m0 + i;
        if constexpr (DR) {
            #pragma unroll
            for (int j = 0; j < 4; j++) {
                int gn = bn + n0 + j;
                Dv[dbase + (size_t)gm * sDm + (size_t)gn * sDn] = accR[i][j] + bz;
            }
        } else {
            // all complex-output call sites use sDn == 1: vectorize 2x float4
            size_t off = dbase + (size_t)gm * sDm + (size_t)(bn + n0);
            float4 s0 = make_float4(accR[i][0], accI[i][0], accR[i][1], accI[i][1]);
            float4 s1 = make_float4(accR[i][2], accI[i][2], accR[i][3], accI[i][3]);
            *(float4*)&((float2*)Dv)[off]     = s0;
            *(float4*)&((float2*)Dv)[off + 2] = s1;
        }
    }
}

// ---------------------------------------------------------------------------
// In-place channel mix on half-spectrum, one (pt, image) per thread:
//   F2[m*8+o][pt] = sum_i F2[m*8+i][pt] * Ke[i*8+o][pt]
// ---------------------------------------------------------------------------
__global__ __launch_bounds__(TPB)
void einsum_k(float2* __restrict__ F2, const float* __restrict__ KeR,
              const float* __restrict__ KeI)
{
    int pt = blockIdx.x * TPB + threadIdx.x;    // [0, 131072)
    float2* F = F2 + (size_t)blockIdx.y * (8 * 131072);

    float xr[8], xi[8];
    #pragma unroll
    for (int i = 0; i < 8; i++) {
        float2 v = F[(size_t)i * 131072 + pt];
        xr[i] = v.x; xi[i] = v.y;
    }
    float ar[8] = {0.f}, ai[8] = {0.f};
    #pragma unroll
    for (int i = 0; i < 8; i++) {
        #pragma unroll
        for (int o = 0; o < 8; o++) {
            float kr = KeR[(size_t)(i * 8 + o) * 131072 + pt];
            float ki = KeI[(size_t)(i * 8 + o) * 131072 + pt];
            ar[o] = fmaf(xr[i], kr, ar[o]);
            ar[o] = fmaf(-xi[i], ki, ar[o]);
            ai[o] = fmaf(xr[i], ki, ai[o]);
            ai[o] = fmaf(xi[i], kr, ai[o]);
        }
    }
    #pragma unroll
    for (int o = 0; o < 8; o++)
        F[(size_t)o * 131072 + pt] = make_float2(ar[o], ai[o]);
}

// ---------------------------------------------------------------------------

extern "C" void kernel_launch(void* const* d_in, const int* in_sizes, int n_in,
                              void* d_out, int out_size, void* d_ws, size_t ws_size,
                              hipStream_t stream) {
    const float* x    = (const float*)d_in[0];
    const float* Kr   = (const float*)d_in[1];
    const float* Ki   = Kr + 16711744;          // 511*511*64
    const float* bias = (const float*)d_in[2];
    float* out = (float*)d_out;
    char* ws = (char*)d_ws;

    float2* Atab   = (float2*)(ws + 0);          //  1,048,576
    float2* AtabTh = (float2*)(ws + 1048576);    //    524,288
    float2* Ctab   = (float2*)(ws + 1572864);    //  1,048,576
    float2* Ct2T   = (float2*)(ws + 2621440);    //    524,288
    float*  xT     = (float*) (ws + 3145728);    // 16,777,216
    float*  KeR    = (float*) (ws + 19922944);   // 33,554,432
    float*  KeI    = (float*) (ws + 53477376);   // 33,554,432
    const size_t fixedEnd = 87031808;

    int g = 1;
    for (int cand = 8; cand >= 1; cand >>= 1) {
        if (fixedEnd + (size_t)cand * 16777216 <= ws_size) { g = cand; break; }
    }
    float2* F1 = (float2*)(ws + fixedEnd);                        // g*8,388,608
    float2* F2 = (float2*)(ws + fixedEnd + (size_t)g * 8388608);  // g*8,388,608

    build_tables_k<<<512, TPB, 0, stream>>>(Atab, AtabTh, Ctab, Ct2T);
    transpose_x_k<<<2048, TPB, 0, stream>>>((const float4*)x, xT);
    ksym_k<<<2044, TPB, 0, stream>>>(Kr, Ki, KeR, KeI);

    for (int b0 = 0; b0 < 8; b0 += g) {
        int Z = g * 8;
        // S1: F1[z][k1*256+w] = sum_n Atab[k1,n]*x[z][n][w]   (B real)
        cgemm_k<false, false><<<dim3(4, 4, Z), TPB, 0, stream>>>(
            256, Atab, 256, 0,
            (const float2*)xT + (size_t)b0 * 8 * 32768, 256, 32768,
            (float*)F1, 256, 1, 1048576, 131072, nullptr);

        // S2: F2[z][k1*256+k2] = sum_w F1[z][k1*256+w]*AtabTh[w*256+k2]
        cgemm_k<true, false><<<dim3(4, 4, Z), TPB, 0, stream>>>(
            256, F1, 256, 131072,
            AtabTh, 256, 0,
            (float*)F2, 256, 1, 1048576, 131072, nullptr);

        // S3: in-place channel mix
        einsum_k<<<dim3(512, g), TPB, 0, stream>>>(F2, KeR, KeI);

        // S4: F1[z][p*256+k2] = sum_k1 Ctab[p*512+k1]*F2[z][k1*256+k2]
        cgemm_k<true, false><<<dim3(4, 2, Z), TPB, 0, stream>>>(
            512, Ctab, 512, 0,
            F2, 256, 131072,
            (float*)F1, 256, 1, 1048576, 131072, nullptr);

        // S5: out[m][p][q][o] = Re(sum_k2 F1[z][p*256+k2]*Ct2T[k2*256+q]) + bias[o]
        cgemm_k<true, true><<<dim3(4, 2, Z), TPB, 0, stream>>>(
            256, F1, 256, 131072,
            Ct2T, 256, 0,
            out + (size_t)b0 * 524288, 2048, 8, 524288, 1, bias);
    }
}

// Round 2
// 509.467 us; speedup vs baseline: 2.0913x; 2.0913x over previous
//
#include <hip/hip_runtime.h>

#define TPB 256

// ---------------------------------------------------------------------------
// B=8, H=W=256, Cin=Cout=8, N=511 (=2H-1), crop offset 127.
// f16x3 split-precision MFMA pipeline (v_mfma_f32_32x32x16_f16):
//   every complex matrix is stored as 4 f16 planes (rh, rl, ih, il) with
//   x = hi + lo exact split; a*b ~= ah*bh + ah*bl + al*bh (al*bl ~2^-22, dropped).
// Stages (per z = (b, channel)):
//   S1: F1[k1][w]   = sum_n  Atab[k1][n] * x[n][w]          (B real)
//   S2: F2T[k2][k1] = sum_w  Atab[k2][w] * F1[k1][w]        (output transposed)
//   S3: einsum channel mix on F2T, Ke = 0.5*w(k2)*(Kc + conj(Kc(-k)))
//   S4: F1p[p][k2]  = sum_k1 Ctab[p][k1] * F2T[k2][k1]
//   S5: Dq[p][q]    = Re sum_k2 F1p[p][k2] * Ct2[q][k2]     (real out, fp32)
//   S6: out[b][p][q][o] = Dq/(511^2) + bias[o]              (transpose-out)
// Scales: tables are unit twiddles; 0.5*w(k2) folded into Ke; 1/511^2 in S6.
// ---------------------------------------------------------------------------

typedef _Float16 half8  __attribute__((ext_vector_type(8)));
typedef _Float16 half2v __attribute__((ext_vector_type(2)));
typedef float    floatx16 __attribute__((ext_vector_type(16)));
typedef unsigned int uintx4 __attribute__((ext_vector_type(4)));

__device__ __forceinline__ void split16(float v, _Float16& h, _Float16& l) {
    h = (_Float16)v;
    l = (_Float16)(v - (float)h);
}

// ---------------------------------------------------------------------------
// Tables, 4-plane f16 (plane stride noted):
// Atab [4][512][256]: [k][n] = exp(-2*pi*i*k*n/511), row 511 = 0
//   (rows 0..255 double as S2's A: exp(-2*pi*i*k2*w/511))
// Ctab [4][256][512]: [p][k1] = exp(+2*pi*i*k1*(p+127)/511), col 511 = 0
// Ct2  [4][256][256]: [q][k2] = exp(+2*pi*i*k2*(q+127)/511)
// ---------------------------------------------------------------------------
__global__ __launch_bounds__(TPB)
void build_tables_k(_Float16* __restrict__ At, _Float16* __restrict__ Ct,
                    _Float16* __restrict__ C2) {
    int idx = blockIdx.x * TPB + threadIdx.x;   // [0, 131072)
    const float w = (float)(6.28318530717958647692 / 511.0);
    {
        int k = idx >> 8, n = idx & 255;
        float cr = 0.f, ci = 0.f;
        if (k < 511) {
            int m = (k * n) % 511;
            float s, c; sincosf(w * (float)m, &s, &c);
            cr = c; ci = -s;
        }
        _Float16 h, l;
        split16(cr, h, l); At[idx] = h; At[131072 + idx] = l;
        split16(ci, h, l); At[262144 + idx] = h; At[393216 + idx] = l;
    }
    {
        int p = idx >> 9, k1 = idx & 511;
        float cr = 0.f, ci = 0.f;
        if (k1 < 511) {
            int m = (k1 * (p + 127)) % 511;
            float s, c; sincosf(w * (float)m, &s, &c);
            cr = c; ci = s;
        }
        _Float16 h, l;
        split16(cr, h, l); Ct[idx] = h; Ct[131072 + idx] = l;
        split16(ci, h, l); Ct[262144 + idx] = h; Ct[393216 + idx] = l;
    }
    if (idx < 65536) {
        int q = idx >> 8, k2 = idx & 255;
        int m = (k2 * (q + 127)) % 511;
        float s, c; sincosf(w * (float)m, &s, &c);
        _Float16 h, l;
        split16(c, h, l); C2[idx] = h; C2[65536 + idx] = l;
        split16(s, h, l); C2[131072 + idx] = h; C2[196608 + idx] = l;
    }
}

// ---------------------------------------------------------------------------
// x [b][n][w][i] fp32 -> xT [z=(b,i)][2 planes h/l][w*256 + n] f16  (B^T for S1)
// ---------------------------------------------------------------------------
__global__ __launch_bounds__(TPB)
void txp_k(const float* __restrict__ x, _Float16* __restrict__ xT) {
    __shared__ _Float16 L[8][2][32][34];
    const int tid = threadIdx.x;
    const int b = blockIdx.z, n0 = blockIdx.y * 32, w0 = blockIdx.x * 32;
    #pragma unroll
    for (int pp = 0; pp < 4; pp++) {
        int w = tid & 31, n = pp * 8 + (tid >> 5);
        const float4* src = (const float4*)(x + ((size_t)((b * 256 + n0 + n) * 256) + w0 + w) * 8);
        float4 v0 = src[0], v1 = src[1];
        float vv[8] = {v0.x, v0.y, v0.z, v0.w, v1.x, v1.y, v1.z, v1.w};
        #pragma unroll
        for (int ch = 0; ch < 8; ch++) {
            _Float16 h, lo; split16(vv[ch], h, lo);
            L[ch][0][w][n] = h;
            L[ch][1][w][n] = lo;
        }
    }
    __syncthreads();
    #pragma unroll
    for (int rr = 0; rr < 2; rr++) {
        int r = tid * 2 + rr;           // 512 rows: ch(8) x pl(2) x w(32)
        int ch = r >> 6, pl = (r >> 5) & 1, w = r & 31;
        const _Float16* row = &L[ch][pl][w][0];
        size_t off = ((size_t)((b * 8 + ch) * 2 + pl)) * 65536 + (size_t)(w0 + w) * 256 + n0;
        #pragma unroll
        for (int cc = 0; cc < 4; cc++) {
            uintx4 u;
            #pragma unroll
            for (int c = 0; c < 4; c++) u[c] = *(const unsigned int*)(row + cc * 8 + c * 2);
            *(uintx4*)(xT + off + cc * 8) = u;
        }
    }
}

// ---------------------------------------------------------------------------
// Hermitian-symmetrized kernel, fp32, einsum-order layout:
//   KeR/KeI [io 64][k2*512 + k1], k1 in [0,512) (col 511 = 0)
//   Ke = 0.5*w(k2)*(Kc(k1,k2) + conj(Kc(k1m,k2m))), w(0)=1 else 2.
// ---------------------------------------------------------------------------
__global__ __launch_bounds__(TPB)
void ksym_k(const float* __restrict__ Kr, const float* __restrict__ Ki,
            float* __restrict__ KeR, float* __restrict__ KeI) {
    __shared__ float LR[64][65];
    __shared__ float LI[64][65];
    const int tid = threadIdx.x;
    const int k2  = blockIdx.x >> 3;
    const int k1g = (blockIdx.x & 7) * 64;
    const int k2m = (k2 == 0) ? 0 : 511 - k2;
    const float sc = (k2 == 0) ? 0.5f : 1.0f;   // 0.5 * w(k2)
    #pragma unroll
    for (int t = 0; t < 4; t++) {
        int idx = tid + t * 256;        // 1024 = 16 j x 64 k1l
        int j = idx & 15, k1l = idx >> 4;
        int k1 = k1g + k1l;
        float4 rs = {0,0,0,0}, rm = {0,0,0,0}, is = {0,0,0,0}, im = {0,0,0,0};
        if (k1 < 511) {
            int k1m = (k1 == 0) ? 0 : 511 - k1;
            size_t so = ((size_t)(k1  * 511 + k2 )) * 64 + j * 4;
            size_t mo = ((size_t)(k1m * 511 + k2m)) * 64 + j * 4;
            rs = *(const float4*)(Kr + so);
            rm = *(const float4*)(Kr + mo);
            is = *(const float4*)(Ki + so);
            im = *(const float4*)(Ki + mo);
        }
        LR[j*4+0][k1l] = sc * (rs.x + rm.x);
        LR[j*4+1][k1l] = sc * (rs.y + rm.y);
        LR[j*4+2][k1l] = sc * (rs.z + rm.z);
        LR[j*4+3][k1l] = sc * (rs.w + rm.w);
        LI[j*4+0][k1l] = sc * (is.x - im.x);
        LI[j*4+1][k1l] = sc * (is.y - im.y);
        LI[j*4+2][k1l] = sc * (is.z - im.z);
        LI[j*4+3][k1l] = sc * (is.w - im.w);
    }
    __syncthreads();
    const size_t ob = (size_t)k2 * 512 + k1g;
    #pragma unroll
    for (int t = 0; t < 4; t++) {
        int idx = tid + t * 256;        // 1024 = 16 fq x 64 io
        int io = idx >> 4, fq = idx & 15;
        float4 vr = make_float4(LR[io][fq*4], LR[io][fq*4+1], LR[io][fq*4+2], LR[io][fq*4+3]);
        float4 vi = make_float4(LI[io][fq*4], LI[io][fq*4+1], LI[io][fq*4+2], LI[io][fq*4+3]);
        *(float4*)(KeR + (size_t)io * 131072 + ob + fq * 4) = vr;
        *(float4*)(KeI + (size_t)io * 131072 + ob + fq * 4) = vi;
    }
}

// ---------------------------------------------------------------------------
// Split-f16 MFMA GEMM. Block 128x128, 4 waves of 64x64 (2x2 32x32 tiles),
// BK=16, v_mfma_f32_32x32x16_f16.
// A complex [plane][M][K] (row stride K); B given TRANSPOSED [plane][N][K].
// LDS: stride 24 f16 (48B), XOR swizzle on the two 8-f16 k-halves -> <=2-way.
// BREAL: B has 2 planes (h,l). DREAL: real fp32 output only (Df).
// ---------------------------------------------------------------------------
template<bool BREAL, bool DREAL>
__global__ __launch_bounds__(TPB, 2)
void mgemm_k(int K,
             const _Float16* __restrict__ Ap, long sAz, long sAp,
             const _Float16* __restrict__ Bp, long sBz, long sBp,
             _Float16* __restrict__ Dp, long sDz, long sDp, int Dn,
             float* __restrict__ Df, long sFz)
{
    __shared__ _Float16 sm[24576];      // A: 4*128*24 @0, B: 4*128*24 @12288

    const int tid = threadIdx.x;
    const int bm = blockIdx.y * 128, bn = blockIdx.x * 128;
    const int z = blockIdx.z;
    const _Float16* A = Ap + (size_t)z * sAz;
    const _Float16* B = Bp + (size_t)z * sBz;

    const int l  = tid & 63;
    const int wv = tid >> 6;
    const int lr = l & 31, lg = l >> 5;
    const int wm = (wv >> 1) * 64, wn = (wv & 1) * 64;

    floatx16 accR[2][2], accI[2][2];
    #pragma unroll
    for (int i = 0; i < 2; i++)
        #pragma unroll
        for (int j = 0; j < 2; j++)
            #pragma unroll
            for (int r = 0; r < 16; r++) {
                accR[i][j][r] = 0.f;
                accI[i][j][r] = 0.f;
            }

    // staging descriptors (uintx4 = 8 f16 chunk); A: 1024 chunks, B: 512/1024
    const _Float16* aPtr[4];
    int aLds[4];
    #pragma unroll
    for (int j = 0; j < 4; j++) {
        int c = tid + j * 256;
        int p = c >> 8, rem = c & 255, row = rem >> 1, kq = rem & 1;
        aPtr[j] = A + (size_t)p * sAp + (size_t)(bm + row) * K + kq * 8;
        aLds[j] = p * 3072 + row * 24 + ((kq ^ (((row >> 3) ^ (row >> 4)) & 1)) * 8);
    }
    const int NBC = BREAL ? 2 : 4;
    const _Float16* bPtr[4];
    int bLds[4];
    #pragma unroll
    for (int j = 0; j < 4; j++) {
        if (j < NBC) {
            int c = tid + j * 256;
            int p = c >> 8, rem = c & 255, col = rem >> 1, kq = rem & 1;
            bPtr[j] = B + (size_t)p * sBp + (size_t)(bn + col) * K + kq * 8;
            bLds[j] = 12288 + p * 3072 + col * 24 + ((kq ^ (((col >> 3) ^ (col >> 4)) & 1)) * 8);
        }
    }

    // loop-invariant fragment offsets (f16 units)
    int aOff[2][4], bOff[2][4];
    #pragma unroll
    for (int mt = 0; mt < 2; mt++) {
        int R = wm + mt * 32 + lr;
        int sw = ((R >> 3) ^ (R >> 4)) & 1;
        #pragma unroll
        for (int p = 0; p < 4; p++)
            aOff[mt][p] = p * 3072 + R * 24 + ((lg ^ sw) * 8);
    }
    #pragma unroll
    for (int nt = 0; nt < 2; nt++) {
        int Cc = wn + nt * 32 + lr;
        int sw = ((Cc >> 3) ^ (Cc >> 4)) & 1;
        #pragma unroll
        for (int p = 0; p < 4; p++)
            bOff[nt][p] = 12288 + p * 3072 + Cc * 24 + ((lg ^ sw) * 8);
    }

    for (int k0 = 0; k0 < K; k0 += 16) {
        #pragma unroll
        for (int j = 0; j < 4; j++) {
            uintx4 v = *(const uintx4*)aPtr[j]; aPtr[j] += 16;
            *(uintx4*)(sm + aLds[j]) = v;
        }
        #pragma unroll
        for (int j = 0; j < 4; j++) {
            if (j < NBC) {
                uintx4 v = *(const uintx4*)bPtr[j]; bPtr[j] += 16;
                *(uintx4*)(sm + bLds[j]) = v;
            }
        }
        __syncthreads();

        half8 a[2][4];
        #pragma unroll
        for (int mt = 0; mt < 2; mt++)
            #pragma unroll
            for (int p = 0; p < 4; p++)
                a[mt][p] = *(const half8*)(sm + aOff[mt][p]);

        half8 nai[2][2];                // -ih, -il (for the -Ai*Bi term)
        if constexpr (!BREAL) {
            #pragma unroll
            for (int mt = 0; mt < 2; mt++)
                #pragma unroll
                for (int p = 0; p < 2; p++) {
                    uintx4 u = __builtin_bit_cast(uintx4, a[mt][2 + p]);
                    u ^= 0x80008000u;
                    nai[mt][p] = __builtin_bit_cast(half8, u);
                }
        }

        #pragma unroll
        for (int nt = 0; nt < 2; nt++) {
            half8 b0 = *(const half8*)(sm + bOff[nt][0]);
            half8 b1 = *(const half8*)(sm + bOff[nt][1]);
            half8 b2, b3;
            if constexpr (!BREAL) {
                b2 = *(const half8*)(sm + bOff[nt][2]);
                b3 = *(const half8*)(sm + bOff[nt][3]);
            }
            #pragma unroll
            for (int mt = 0; mt < 2; mt++) {
                if constexpr (BREAL) {
                    // Cr = Ar*B ; Ci = Ai*B
                    accR[mt][nt] = __builtin_amdgcn_mfma_f32_32x32x16_f16(a[mt][0], b0, accR[mt][nt], 0, 0, 0);
                    accR[mt][nt] = __builtin_amdgcn_mfma_f32_32x32x16_f16(a[mt][0], b1, accR[mt][nt], 0, 0, 0);
                    accR[mt][nt] = __builtin_amdgcn_mfma_f32_32x32x16_f16(a[mt][1], b0, accR[mt][nt], 0, 0, 0);
                    accI[mt][nt] = __builtin_amdgcn_mfma_f32_32x32x16_f16(a[mt][2], b0, accI[mt][nt], 0, 0, 0);
                    accI[mt][nt] = __builtin_amdgcn_mfma_f32_32x32x16_f16(a[mt][2], b1, accI[mt][nt], 0, 0, 0);
                    accI[mt][nt] = __builtin_amdgcn_mfma_f32_32x32x16_f16(a[mt][3], b0, accI[mt][nt], 0, 0, 0);
                } else if constexpr (DREAL) {
                    // Cr = Ar*Br - Ai*Bi
                    accR[mt][nt] = __builtin_amdgcn_mfma_f32_32x32x16_f16(a[mt][0], b0, accR[mt][nt], 0, 0, 0);
                    accR[mt][nt] = __builtin_amdgcn_mfma_f32_32x32x16_f16(a[mt][0], b1, accR[mt][nt], 0, 0, 0);
                    accR[mt][nt] = __builtin_amdgcn_mfma_f32_32x32x16_f16(a[mt][1], b0, accR[mt][nt], 0, 0, 0);
                    accR[mt][nt] = __builtin_amdgcn_mfma_f32_32x32x16_f16(nai[mt][0], b2, accR[mt][nt], 0, 0, 0);
                    accR[mt][nt] = __builtin_amdgcn_mfma_f32_32x32x16_f16(nai[mt][0], b3, accR[mt][nt], 0, 0, 0);
                    accR[mt][nt] = __builtin_amdgcn_mfma_f32_32x32x16_f16(nai[mt][1], b2, accR[mt][nt], 0, 0, 0);
                } else {
                    accR[mt][nt] = __builtin_amdgcn_mfma_f32_32x32x16_f16(a[mt][0], b0, accR[mt][nt], 0, 0, 0);
                    accR[mt][nt] = __builtin_amdgcn_mfma_f32_32x32x16_f16(a[mt][0], b1, accR[mt][nt], 0, 0, 0);
                    accR[mt][nt] = __builtin_amdgcn_mfma_f32_32x32x16_f16(a[mt][1], b0, accR[mt][nt], 0, 0, 0);
                    accR[mt][nt] = __builtin_amdgcn_mfma_f32_32x32x16_f16(nai[mt][0], b2, accR[mt][nt], 0, 0, 0);
                    accR[mt][nt] = __builtin_amdgcn_mfma_f32_32x32x16_f16(nai[mt][0], b3, accR[mt][nt], 0, 0, 0);
                    accR[mt][nt] = __builtin_amdgcn_mfma_f32_32x32x16_f16(nai[mt][1], b2, accR[mt][nt], 0, 0, 0);
                    accI[mt][nt] = __builtin_amdgcn_mfma_f32_32x32x16_f16(a[mt][0], b2, accI[mt][nt], 0, 0, 0);
                    accI[mt][nt] = __builtin_amdgcn_mfma_f32_32x32x16_f16(a[mt][0], b3, accI[mt][nt], 0, 0, 0);
                    accI[mt][nt] = __builtin_amdgcn_mfma_f32_32x32x16_f16(a[mt][1], b2, accI[mt][nt], 0, 0, 0);
                    accI[mt][nt] = __builtin_amdgcn_mfma_f32_32x32x16_f16(a[mt][2], b0, accI[mt][nt], 0, 0, 0);
                    accI[mt][nt] = __builtin_amdgcn_mfma_f32_32x32x16_f16(a[mt][2], b1, accI[mt][nt], 0, 0, 0);
                    accI[mt][nt] = __builtin_amdgcn_mfma_f32_32x32x16_f16(a[mt][3], b0, accI[mt][nt], 0, 0, 0);
                }
            }
        }
        __syncthreads();
    }

    // epilogue: C/D layout col = lane&31, row = (r&3) + 8*(r>>2) + 4*(lane>>5)
    if constexpr (DREAL) {
        float* D = Df + (size_t)z * sFz;
        #pragma unroll
        for (int mt = 0; mt < 2; mt++)
            #pragma unroll
            for (int nt = 0; nt < 2; nt++)
                #pragma unroll
                for (int r = 0; r < 16; r++) {
                    int row = bm + wm + mt * 32 + (r & 3) + 8 * (r >> 2) + 4 * lg;
                    int col = bn + wn + nt * 32 + lr;
                    D[(size_t)row * Dn + col] = accR[mt][nt][r];
                }
    } else {
        _Float16* D = Dp + (size_t)z * sDz;
        #pragma unroll
        for (int mt = 0; mt < 2; mt++)
            #pragma unroll
            for (int nt = 0; nt < 2; nt++)
                #pragma unroll
                for (int r = 0; r < 16; r++) {
                    int row = bm + wm + mt * 32 + (r & 3) + 8 * (r >> 2) + 4 * lg;
                    int col = bn + wn + nt * 32 + lr;
                    size_t base = (size_t)row * Dn + col;
                    _Float16 h, lo;
                    split16(accR[mt][nt][r], h, lo);
                    D[base] = h;
                    D[sDp + base] = lo;
                    split16(accI[mt][nt][r], h, lo);
                    D[2 * sDp + base] = h;
                    D[3 * sDp + base] = lo;
                }
    }
}

// ---------------------------------------------------------------------------
// Channel mix on F2T (split-f16 planes), all g images per thread, 2 pts each.
// ---------------------------------------------------------------------------
__global__ __launch_bounds__(TPB)
void einsum_k(_Float16* __restrict__ F, const float* __restrict__ KeR,
              const float* __restrict__ KeI, int g)
{
    const int pt = (blockIdx.x * TPB + threadIdx.x) * 2;
    for (int b = 0; b < g; b++) {
        _Float16* Fb = F + (size_t)b * 4194304;
        float xr0[8], xr1[8], xi0[8], xi1[8];
        #pragma unroll
        for (int i = 0; i < 8; i++) {
            const _Float16* P = Fb + (size_t)i * 524288 + pt;
            half2v rh = *(const half2v*)(P);
            half2v rl = *(const half2v*)(P + 131072);
            half2v ih = *(const half2v*)(P + 262144);
            half2v il = *(const half2v*)(P + 393216);
            xr0[i] = (float)rh.x + (float)rl.x;
            xr1[i] = (float)rh.y + (float)rl.y;
            xi0[i] = (float)ih.x + (float)il.x;
            xi1[i] = (float)ih.y + (float)il.y;
        }
        #pragma unroll
        for (int o = 0; o < 8; o++) {
            float ar0 = 0.f, ar1 = 0.f, ai0 = 0.f, ai1 = 0.f;
            #pragma unroll
            for (int i = 0; i < 8; i++) {
                const size_t ko = (size_t)(i * 8 + o) * 131072 + pt;
                float2 kr = *(const float2*)(KeR + ko);
                float2 ki = *(const float2*)(KeI + ko);
                ar0 = fmaf(xr0[i], kr.x, ar0); ar0 = fmaf(-xi0[i], ki.x, ar0);
                ai0 = fmaf(xr0[i], ki.x, ai0); ai0 = fmaf(xi0[i], kr.x, ai0);
                ar1 = fmaf(xr1[i], kr.y, ar1); ar1 = fmaf(-xi1[i], ki.y, ar1);
                ai1 = fmaf(xr1[i], ki.y, ai1); ai1 = fmaf(xi1[i], kr.y, ai1);
            }
            _Float16* Q = Fb + (size_t)o * 524288 + pt;
            _Float16 h0, l0, h1, l1;
            split16(ar0, h0, l0); split16(ar1, h1, l1);
            { half2v v = {h0, h1}; *(half2v*)(Q) = v; }
            { half2v v = {l0, l1}; *(half2v*)(Q + 131072) = v; }
            split16(ai0, h0, l0); split16(ai1, h1, l1);
            { half2v v = {h0, h1}; *(half2v*)(Q + 262144) = v; }
            { half2v v = {l0, l1}; *(half2v*)(Q + 393216) = v; }
        }
    }
}

// ---------------------------------------------------------------------------
// out[b][p][q][o] = Dq[(bl*8+o)][p*256+q] / 511^2 + bias[o]
// ---------------------------------------------------------------------------
__global__ __launch_bounds__(TPB)
void tout_k(const float* __restrict__ Dq, const float* __restrict__ bias,
            float* __restrict__ out, int b0)
{
    int idx = blockIdx.x * TPB + threadIdx.x;
    int o = idx & 7, q = (idx >> 3) & 255, p = (idx >> 11) & 255, bl = idx >> 19;
    float v = Dq[(size_t)(bl * 8 + o) * 65536 + p * 256 + q];
    out[(size_t)(b0 + bl) * 524288 + (size_t)(idx & 524287)] = v * (1.f / 261121.f) + bias[o];
}

// ---------------------------------------------------------------------------

extern "C" void kernel_launch(void* const* d_in, const int* in_sizes, int n_in,
                              void* d_out, int out_size, void* d_ws, size_t ws_size,
                              hipStream_t stream) {
    const float* x    = (const float*)d_in[0];
    const float* Kr   = (const float*)d_in[1];
    const float* Ki   = Kr + 16711744;          // 511*511*64
    const float* bias = (const float*)d_in[2];
    float* out = (float*)d_out;
    char* ws = (char*)d_ws;

    _Float16* Atab = (_Float16*)(ws + 0);            //  1,048,576
    _Float16* Ctab = (_Float16*)(ws + 1048576);      //  1,048,576
    _Float16* Ct2  = (_Float16*)(ws + 2097152);      //    524,288
    _Float16* xTp  = (_Float16*)(ws + 2621440);      // 16,777,216
    float*    KeR  = (float*)   (ws + 19398656);     // 33,554,432
    float*    KeI  = (float*)   (ws + 52953088);     // 33,554,432
    const size_t fixedEnd = 86507520;

    int g = 1;
    for (int cand = 8; cand >= 1; cand >>= 1) {
        if (fixedEnd + (size_t)cand * 16777216 <= ws_size) { g = cand; break; }
    }
    _Float16* F1  = (_Float16*)(ws + fixedEnd);                        // g*8 MB
    _Float16* F2T = (_Float16*)(ws + fixedEnd + (size_t)g * 8388608);  // g*8 MB
    _Float16* F1b = F1;                 // alias: F1 dead after S2
    float*    Dq  = (float*)F2T;        // alias: F2T dead after S4

    build_tables_k<<<512, TPB, 0, stream>>>(Atab, Ctab, Ct2);
    txp_k<<<dim3(8, 8, 8), TPB, 0, stream>>>(x, xTp);
    ksym_k<<<2048, TPB, 0, stream>>>(Kr, Ki, KeR, KeI);

    for (int b0 = 0; b0 < 8; b0 += g) {
        int Z = g * 8;
        // S1: F1 = Atab(512x256) * x   (B real, BT = xTp[w][n])
        mgemm_k<true, false><<<dim3(2, 4, Z), TPB, 0, stream>>>(
            256, Atab, 0, 131072,
            xTp + (size_t)b0 * 8 * 131072, 131072, 65536,
            F1, 524288, 131072, 256, nullptr, 0);

        // S2: F2T[k2][k1] = Atab(256x256) * F1^T  (BT = F1[k1][w])
        mgemm_k<false, false><<<dim3(4, 2, Z), TPB, 0, stream>>>(
            256, Atab, 0, 131072,
            F1, 524288, 131072,
            F2T, 524288, 131072, 512, nullptr, 0);

        // S3: channel mix
        einsum_k<<<256, TPB, 0, stream>>>(F2T, KeR, KeI, g);

        // S4: F1'[p][k2] = Ctab(256x512) * F2   (BT = F2T[k2][k1])
        mgemm_k<false, false><<<dim3(2, 2, Z), TPB, 0, stream>>>(
            512, Ctab, 0, 131072,
            F2T, 524288, 131072,
            F1b, 262144, 65536, 256, nullptr, 0);

        // S5: Dq[p][q] = Re(F1' * Ct2^T)   (BT = Ct2[q][k2], fp32 out)
        mgemm_k<false, true><<<dim3(2, 2, Z), TPB, 0, stream>>>(
            256, F1b, 262144, 65536,
            Ct2, 0, 65536,
            nullptr, 0, 0, 256, Dq, 65536);

        // S6: transpose to NHWC + scale + bias
        tout_k<<<g * 2048, TPB, 0, stream>>>(Dq, bias, out, b0);
    }
}

// Round 4
// 504.478 us; speedup vs baseline: 2.1120x; 1.0099x over previous
//
#include <hip/hip_runtime.h>

#define TPB 256

// ---------------------------------------------------------------------------
// B=8, H=W=256, Cin=Cout=8, N=511 (=2H-1), crop offset 127.
// f16x3 split-precision MFMA pipeline (v_mfma_f32_32x32x16_f16):
//   complex values as 4 f16 planes (rh, rl, ih, il), x = hi+lo exact;
//   a*b ~= ah*bh + ah*bl + al*bh (al*bl ~2^-22 dropped).
//
// Layouts:
//  - Twiddle tables in FRAGMENT-NATIVE order [tile32][kc16][plane4][lane64][8]
//    -> wave MFMA fragment = one coalesced 1KB global load (L1/L2-cached),
//    no LDS for the table operand.
//  - Data matrices in chunk-interleaved order [col][kc8][plane][8]
//    -> staging 128B contiguous per col; LDS with slot XOR (2p+h)^(col&7)
//    conflict-free on ds_read_b128/ds_write_b128.
// Stages per z=(img,ch):
//   S1: F1[k1][w]   = sum_n  Atab[k1][n] * x[n][w]          (B real, 2 planes)
//   S2: F2T[k2][k1] = sum_w  Atab[k2][w] * F1[k1][w]
//   S3: einsum channel mix on F2T (Ke = 0.5*w(k2)*(Kc + conj(Kc(-k))), fp32)
//   S4: F1p[p][k2]  = sum_k1 Ctab[p][k1] * F2T[k2][k1]
//   S5: Dq[p][q]    = Re sum_k2 F1p[p][k2] * Ct2[q][k2]     (fp32 out)
//   S6: out = Dq/511^2 + bias (transpose to NHWC)
// ---------------------------------------------------------------------------

typedef _Float16 half8  __attribute__((ext_vector_type(8)));
typedef float    floatx16 __attribute__((ext_vector_type(16)));
typedef unsigned int uintx4 __attribute__((ext_vector_type(4)));

__device__ __forceinline__ void split16(float v, _Float16& h, _Float16& l) {
    h = (_Float16)v;
    l = (_Float16)(v - (float)h);
}

// ---------------------------------------------------------------------------
// Fragment-native tables.
// Atab: M=512 (k1), K=256 (n): exp(-2*pi*i*k1*n/511), row 511 = 0. 1MB.
//       (rows 0..255 double as S2's A over (k2, w))
// Ctab: M=256 (p), K=512 (k1): exp(+2*pi*i*k1*(p+127)/511), k=511 -> 0. 1MB.
// Ct2 : N=256 (q), K=256 (k2): exp(+2*pi*i*k2*(q+127)/511). 512KB.
// Element (R,k,plane p) at: ((tile*(K/16)+kcblk)*4+p)*512 + lane*8 + (k&7),
//   tile=R>>5, kcblk=k>>4, lane=(R&31)+32*((k>>3)&1).
// ---------------------------------------------------------------------------
__global__ __launch_bounds__(TPB)
void build_tables_k(_Float16* __restrict__ At, _Float16* __restrict__ Ct,
                    _Float16* __restrict__ C2) {
    int idx = blockIdx.x * TPB + threadIdx.x;   // [0, 40960)
    const float w = (float)(6.28318530717958647692 / 511.0);
    _Float16* T; int R, kc2, K; int mode;
    if (idx < 16384)      { T = At; R = idx >> 5;  kc2 = idx & 31; K = 256; mode = 0; }
    else if (idx < 32768) { int id = idx - 16384; T = Ct; R = id >> 6; kc2 = id & 63; K = 512; mode = 1; }
    else                  { int id = idx - 32768; T = C2; R = id >> 5; kc2 = id & 31; K = 256; mode = 2; }

    half8 vrh, vrl, vih, vil;
    #pragma unroll
    for (int j = 0; j < 8; j++) {
        int k = kc2 * 8 + j;
        float cr = 0.f, ci = 0.f;
        if (mode == 0) {
            if (R < 511) {
                int m = (R * k) % 511;
                float s, c; sincosf(w * (float)m, &s, &c);
                cr = c; ci = -s;
            }
        } else {
            if (!(mode == 1 && k == 511)) {
                int m = (k * (R + 127)) % 511;
                float s, c; sincosf(w * (float)m, &s, &c);
                cr = c; ci = s;
            }
        }
        _Float16 th, tl;
        split16(cr, th, tl); vrh[j] = th; vrl[j] = tl;
        split16(ci, th, tl); vih[j] = th; vil[j] = tl;
    }
    int tile = R >> 5, kcblk = kc2 >> 1, lane = (R & 31) + 32 * (kc2 & 1);
    size_t base = ((size_t)(tile * (K >> 4) + kcblk) * 4) * 512 + lane * 8;
    *(half8*)(T + base)        = vrh;
    *(half8*)(T + base + 512)  = vrl;
    *(half8*)(T + base + 1024) = vih;
    *(half8*)(T + base + 1536) = vil;
}

// ---------------------------------------------------------------------------
// x [b][n][w][i] fp32 -> xTp [z=(b,i)][col=w][kc=n>>3][plane2][8]
// ---------------------------------------------------------------------------
__global__ __launch_bounds__(TPB)
void txp_k(const float* __restrict__ x, _Float16* __restrict__ xT) {
    __shared__ _Float16 L[8][2][32][40];
    const int tid = threadIdx.x;
    const int b = blockIdx.z, n0 = blockIdx.y * 32, w0 = blockIdx.x * 32;
    #pragma unroll
    for (int pp = 0; pp < 4; pp++) {
        int w = tid & 31, n = pp * 8 + (tid >> 5);
        const float4* src = (const float4*)(x + ((size_t)((b * 256 + n0 + n) * 256) + w0 + w) * 8);
        float4 v0 = src[0], v1 = src[1];
        float vv[8] = {v0.x, v0.y, v0.z, v0.w, v1.x, v1.y, v1.z, v1.w};
        #pragma unroll
        for (int ch = 0; ch < 8; ch++) {
            _Float16 h, lo; split16(vv[ch], h, lo);
            L[ch][0][w][n] = h;
            L[ch][1][w][n] = lo;
        }
    }
    __syncthreads();
    #pragma unroll
    for (int t = 0; t < 8; t++) {
        int c = tid + t * 256;          // 2048 chunks: [ch][w][cc][p]
        int p = c & 1, cc = (c >> 1) & 3, w = (c >> 3) & 31, ch = c >> 8;
        uintx4 v = *(const uintx4*)&L[ch][p][w][cc * 8];
        size_t off = ((size_t)(b * 8 + ch)) * 131072 + (size_t)(w0 + w) * 512
                   + (size_t)((n0 >> 3) + cc) * 16 + p * 8;
        *(uintx4*)(xT + off) = v;
    }
}

// ---------------------------------------------------------------------------
// Hermitian-symmetrized kernel, fp32: KeR/KeI [io64][k2*512 + k1]
// Ke = 0.5*w(k2)*(Kc(k1,k2) + conj(Kc(-k1,-k2))), w(0)=1 else 2.
// ---------------------------------------------------------------------------
__global__ __launch_bounds__(TPB)
void ksym_k(const float* __restrict__ Kr, const float* __restrict__ Ki,
            float* __restrict__ KeR, float* __restrict__ KeI) {
    __shared__ float LR[64][65];
    __shared__ float LI[64][65];
    const int tid = threadIdx.x;
    const int k2  = blockIdx.x >> 3;
    const int k1g = (blockIdx.x & 7) * 64;
    const int k2m = (k2 == 0) ? 0 : 511 - k2;
    const float sc = (k2 == 0) ? 0.5f : 1.0f;
    #pragma unroll
    for (int t = 0; t < 4; t++) {
        int idx = tid + t * 256;
        int j = idx & 15, k1l = idx >> 4;
        int k1 = k1g + k1l;
        float4 rs = {0,0,0,0}, rm = {0,0,0,0}, is = {0,0,0,0}, im = {0,0,0,0};
        if (k1 < 511) {
            int k1m = (k1 == 0) ? 0 : 511 - k1;
            size_t so = ((size_t)(k1  * 511 + k2 )) * 64 + j * 4;
            size_t mo = ((size_t)(k1m * 511 + k2m)) * 64 + j * 4;
            rs = *(const float4*)(Kr + so);
            rm = *(const float4*)(Kr + mo);
            is = *(const float4*)(Ki + so);
            im = *(const float4*)(Ki + mo);
        }
        LR[j*4+0][k1l] = sc * (rs.x + rm.x);
        LR[j*4+1][k1l] = sc * (rs.y + rm.y);
        LR[j*4+2][k1l] = sc * (rs.z + rm.z);
        LR[j*4+3][k1l] = sc * (rs.w + rm.w);
        LI[j*4+0][k1l] = sc * (is.x - im.x);
        LI[j*4+1][k1l] = sc * (is.y - im.y);
        LI[j*4+2][k1l] = sc * (is.z - im.z);
        LI[j*4+3][k1l] = sc * (is.w - im.w);
    }
    __syncthreads();
    const size_t ob = (size_t)k2 * 512 + k1g;
    #pragma unroll
    for (int t = 0; t < 4; t++) {
        int idx = tid + t * 256;
        int io = idx >> 4, fq = idx & 15;
        float4 vr = make_float4(LR[io][fq*4], LR[io][fq*4+1], LR[io][fq*4+2], LR[io][fq*4+3]);
        float4 vi = make_float4(LI[io][fq*4], LI[io][fq*4+1], LI[io][fq*4+2], LI[io][fq*4+3]);
        *(float4*)(KeR + (size_t)io * 131072 + ob + fq * 4) = vr;
        *(float4*)(KeI + (size_t)io * 131072 + ob + fq * 4) = vi;
    }
}

// ---------------------------------------------------------------------------
// Split-f16 MFMA GEMM. Block 128x128, 4 waves of 64x64 (2x2 32x32 tiles).
// Table side direct-from-global (fragment-native); data side via LDS
// (chunk-interleaved + slot XOR, conflict-free).
// NPD: data planes (4 complex / 2 real). TBA: table is A. DREAL: fp32 Re out.
// ---------------------------------------------------------------------------
template<int NPD, bool TBA, bool DREAL>
__global__ __launch_bounds__(TPB, 2)
void mgemm_k(int K, const _Float16* __restrict__ Tf,
             const _Float16* __restrict__ Dd, long sDz,
             _Float16* __restrict__ Out, long sOz, int OutKc,
             float* __restrict__ Of, long sOfz, int OfN)
{
    constexpr int SLOTS = NPD * 2;           // 16B slots per col-row
    constexpr int CPT   = NPD;               // staged chunks per thread
    __shared__ _Float16 sm[128 * SLOTS * 8]; // 16KB (NPD4) / 8KB (NPD2)

    const int tid = threadIdx.x;
    const int bm = blockIdx.y * 128, bn = blockIdx.x * 128;
    const int z = blockIdx.z;
    const _Float16* D = Dd + (size_t)z * sDz;

    const int l  = tid & 63;
    const int wv = tid >> 6;
    const int lr = l & 31, lg = l >> 5;
    const int wm = (wv >> 1) * 64, wn = (wv & 1) * 64;
    const int Kc16 = K >> 4;

    // table-side tile bases (A for S1/S2/S4, B for S5)
    const int tb = (TBA ? bm + wm : bn + wn);
    int tTB[2];
    #pragma unroll
    for (int t = 0; t < 2; t++) tTB[t] = ((tb + t * 32) >> 5) * Kc16;

    // data-side fragment LDS offsets
    const int db = (TBA ? wn : wm);
    int dOff[2][NPD];
    #pragma unroll
    for (int t = 0; t < 2; t++) {
        int cl = db + t * 32 + lr;
        int sw = cl & (SLOTS - 1);
        #pragma unroll
        for (int p = 0; p < NPD; p++)
            dOff[t][p] = cl * (NPD * 16) + (((p * 2 + lg) ^ sw) * 8);
    }

    // staging descriptors
    const int bSide = (TBA ? bn : bm);
    const _Float16* gP[CPT];
    int lO[CPT];
    #pragma unroll
    for (int j = 0; j < CPT; j++) {
        int cid = tid + j * TPB;
        int col = cid / SLOTS;
        int inner = cid & (SLOTS - 1);
        int p = inner & (NPD - 1);
        int h = inner / NPD;
        gP[j] = D + ((size_t)(bSide + col) * (K >> 3) + h) * (NPD * 8) + p * 8;
        lO[j] = col * (NPD * 16) + (((p * 2 + h) ^ (col & (SLOTS - 1))) * 8);
    }

    floatx16 accR[2][2], accI[2][2];
    #pragma unroll
    for (int i = 0; i < 2; i++)
        #pragma unroll
        for (int j = 0; j < 2; j++)
            #pragma unroll
            for (int r = 0; r < 16; r++) { accR[i][j][r] = 0.f; accI[i][j][r] = 0.f; }

    // prologue: prefetch step-0 chunks
    uintx4 st[CPT];
    #pragma unroll
    for (int j = 0; j < CPT; j++) { st[j] = *(const uintx4*)gP[j]; gP[j] += NPD * 16; }

    for (int k0 = 0; k0 < K; k0 += 16) {
        #pragma unroll
        for (int j = 0; j < CPT; j++) *(uintx4*)(sm + lO[j]) = st[j];
        __syncthreads();
        if (k0 + 16 < K) {
            #pragma unroll
            for (int j = 0; j < CPT; j++) { st[j] = *(const uintx4*)gP[j]; gP[j] += NPD * 16; }
        }

        const int kc0 = k0 >> 4;
        // table fragments (direct from global, L1/L2-cached, coalesced)
        half8 tf[2][4];
        #pragma unroll
        for (int t = 0; t < 2; t++)
            #pragma unroll
            for (int p = 0; p < 4; p++)
                tf[t][p] = *(const half8*)(Tf + ((size_t)(tTB[t] + kc0) * 4 + p) * 512 + l * 8);
        // data fragments (LDS)
        half8 df[2][NPD];
        #pragma unroll
        for (int t = 0; t < 2; t++)
            #pragma unroll
            for (int p = 0; p < NPD; p++)
                df[t][p] = *(const half8*)(sm + dOff[t][p]);

        if constexpr (TBA && NPD == 4 && !DREAL) {
            // full complex: A=table, B=data
            half8 na[2][2];
            #pragma unroll
            for (int t = 0; t < 2; t++)
                #pragma unroll
                for (int p = 0; p < 2; p++) {
                    uintx4 u = __builtin_bit_cast(uintx4, tf[t][2 + p]);
                    u ^= 0x80008000u;
                    na[t][p] = __builtin_bit_cast(half8, u);
                }
            #pragma unroll
            for (int nt = 0; nt < 2; nt++)
                #pragma unroll
                for (int mt = 0; mt < 2; mt++) {
                    accR[mt][nt] = __builtin_amdgcn_mfma_f32_32x32x16_f16(tf[mt][0], df[nt][0], accR[mt][nt], 0,0,0);
                    accR[mt][nt] = __builtin_amdgcn_mfma_f32_32x32x16_f16(tf[mt][0], df[nt][1], accR[mt][nt], 0,0,0);
                    accR[mt][nt] = __builtin_amdgcn_mfma_f32_32x32x16_f16(tf[mt][1], df[nt][0], accR[mt][nt], 0,0,0);
                    accR[mt][nt] = __builtin_amdgcn_mfma_f32_32x32x16_f16(na[mt][0], df[nt][2], accR[mt][nt], 0,0,0);
                    accR[mt][nt] = __builtin_amdgcn_mfma_f32_32x32x16_f16(na[mt][0], df[nt][3], accR[mt][nt], 0,0,0);
                    accR[mt][nt] = __builtin_amdgcn_mfma_f32_32x32x16_f16(na[mt][1], df[nt][2], accR[mt][nt], 0,0,0);
                    accI[mt][nt] = __builtin_amdgcn_mfma_f32_32x32x16_f16(tf[mt][0], df[nt][2], accI[mt][nt], 0,0,0);
                    accI[mt][nt] = __builtin_amdgcn_mfma_f32_32x32x16_f16(tf[mt][0], df[nt][3], accI[mt][nt], 0,0,0);
                    accI[mt][nt] = __builtin_amdgcn_mfma_f32_32x32x16_f16(tf[mt][1], df[nt][2], accI[mt][nt], 0,0,0);
                    accI[mt][nt] = __builtin_amdgcn_mfma_f32_32x32x16_f16(tf[mt][2], df[nt][0], accI[mt][nt], 0,0,0);
                    accI[mt][nt] = __builtin_amdgcn_mfma_f32_32x32x16_f16(tf[mt][2], df[nt][1], accI[mt][nt], 0,0,0);
                    accI[mt][nt] = __builtin_amdgcn_mfma_f32_32x32x16_f16(tf[mt][3], df[nt][0], accI[mt][nt], 0,0,0);
                }
        } else if constexpr (TBA && NPD == 2) {
            // S1: B real (h,l)
            #pragma unroll
            for (int nt = 0; nt < 2; nt++)
                #pragma unroll
                for (int mt = 0; mt < 2; mt++) {
                    accR[mt][nt] = __builtin_amdgcn_mfma_f32_32x32x16_f16(tf[mt][0], df[nt][0], accR[mt][nt], 0,0,0);
                    accR[mt][nt] = __builtin_amdgcn_mfma_f32_32x32x16_f16(tf[mt][0], df[nt][1], accR[mt][nt], 0,0,0);
                    accR[mt][nt] = __builtin_amdgcn_mfma_f32_32x32x16_f16(tf[mt][1], df[nt][0], accR[mt][nt], 0,0,0);
                    accI[mt][nt] = __builtin_amdgcn_mfma_f32_32x32x16_f16(tf[mt][2], df[nt][0], accI[mt][nt], 0,0,0);
                    accI[mt][nt] = __builtin_amdgcn_mfma_f32_32x32x16_f16(tf[mt][2], df[nt][1], accI[mt][nt], 0,0,0);
                    accI[mt][nt] = __builtin_amdgcn_mfma_f32_32x32x16_f16(tf[mt][3], df[nt][0], accI[mt][nt], 0,0,0);
                }
        } else {
            // S5: A = data (LDS, 4 planes), B = table, Re-only output
            half8 na[2][2];
            #pragma unroll
            for (int t = 0; t < 2; t++)
                #pragma unroll
                for (int p = 0; p < 2; p++) {
                    uintx4 u = __builtin_bit_cast(uintx4, df[t][2 + p]);
                    u ^= 0x80008000u;
                    na[t][p] = __builtin_bit_cast(half8, u);
                }
            #pragma unroll
            for (int nt = 0; nt < 2; nt++)
                #pragma unroll
                for (int mt = 0; mt < 2; mt++) {
                    accR[mt][nt] = __builtin_amdgcn_mfma_f32_32x32x16_f16(df[mt][0], tf[nt][0], accR[mt][nt], 0,0,0);
                    accR[mt][nt] = __builtin_amdgcn_mfma_f32_32x32x16_f16(df[mt][0], tf[nt][1], accR[mt][nt], 0,0,0);
                    accR[mt][nt] = __builtin_amdgcn_mfma_f32_32x32x16_f16(df[mt][1], tf[nt][0], accR[mt][nt], 0,0,0);
                    accR[mt][nt] = __builtin_amdgcn_mfma_f32_32x32x16_f16(na[mt][0], tf[nt][2], accR[mt][nt], 0,0,0);
                    accR[mt][nt] = __builtin_amdgcn_mfma_f32_32x32x16_f16(na[mt][0], tf[nt][3], accR[mt][nt], 0,0,0);
                    accR[mt][nt] = __builtin_amdgcn_mfma_f32_32x32x16_f16(na[mt][1], tf[nt][2], accR[mt][nt], 0,0,0);
                }
        }
        __syncthreads();
    }

    // epilogue: C/D layout col = lane&31, row = (r&3) + 8*(r>>2) + 4*lg
    if constexpr (DREAL) {
        float* Dv = Of + (size_t)z * sOfz;
        #pragma unroll
        for (int mt = 0; mt < 2; mt++)
            #pragma unroll
            for (int nt = 0; nt < 2; nt++)
                #pragma unroll
                for (int r = 0; r < 16; r++) {
                    int row = bm + wm + mt * 32 + (r & 3) + 8 * (r >> 2) + 4 * lg;
                    int col = bn + wn + nt * 32 + lr;
                    Dv[(size_t)row * OfN + col] = accR[mt][nt][r];
                }
    } else {
        _Float16* O = Out + (size_t)z * sOz;
        #pragma unroll
        for (int mt = 0; mt < 2; mt++)
            #pragma unroll
            for (int nt = 0; nt < 2; nt++)
                #pragma unroll
                for (int r = 0; r < 16; r++) {
                    int row = bm + wm + mt * 32 + (r & 3) + 8 * (r >> 2) + 4 * lg;
                    int col = bn + wn + nt * 32 + lr;
                    size_t base = ((size_t)row * OutKc + (col >> 3)) * 32 + (col & 7);
                    _Float16 h, lo;
                    split16(accR[mt][nt][r], h, lo);
                    O[base]      = h;
                    O[base + 8]  = lo;
                    split16(accI[mt][nt][r], h, lo);
                    O[base + 16] = h;
                    O[base + 24] = lo;
                }
    }
}

// ---------------------------------------------------------------------------
// Channel mix on F2T (interleaved layout), image-tiled by 4 to reuse Ke.
// ---------------------------------------------------------------------------
__global__ __launch_bounds__(TPB)
void einsum_k(_Float16* __restrict__ F, const float* __restrict__ KeR,
              const float* __restrict__ KeI, int g)
{
    const int pt = blockIdx.x * TPB + threadIdx.x;   // k2*512 + k1
    const int k2 = pt >> 9, k1 = pt & 511;
    const size_t fo = ((size_t)(k2 * 64 + (k1 >> 3))) * 32 + (k1 & 7);

    for (int b0 = 0; b0 < g; b0 += 4) {
        const int bt = (g - b0 < 4) ? (g - b0) : 4;
        float xr[4][8], xi[4][8];
        #pragma unroll
        for (int bb = 0; bb < 4; bb++) {
            if (bb >= bt) break;
            #pragma unroll
            for (int i = 0; i < 8; i++) {
                const _Float16* P = F + ((size_t)((b0 + bb) * 8 + i)) * 524288 + fo;
                xr[bb][i] = (float)P[0]  + (float)P[8];
                xi[bb][i] = (float)P[16] + (float)P[24];
            }
        }
        #pragma unroll
        for (int o = 0; o < 8; o++) {
            float ar[4] = {0.f,0.f,0.f,0.f}, ai[4] = {0.f,0.f,0.f,0.f};
            #pragma unroll
            for (int i = 0; i < 8; i++) {
                float kr = KeR[(size_t)(i * 8 + o) * 131072 + pt];
                float ki = KeI[(size_t)(i * 8 + o) * 131072 + pt];
                #pragma unroll
                for (int bb = 0; bb < 4; bb++) {
                    ar[bb] = fmaf(xr[bb][i], kr, ar[bb]);
                    ar[bb] = fmaf(-xi[bb][i], ki, ar[bb]);
                    ai[bb] = fmaf(xr[bb][i], ki, ai[bb]);
                    ai[bb] = fmaf(xi[bb][i], kr, ai[bb]);
                }
            }
            #pragma unroll
            for (int bb = 0; bb < 4; bb++) {
                if (bb >= bt) break;
                _Float16* Q = F + ((size_t)((b0 + bb) * 8 + o)) * 524288 + fo;
                _Float16 h, lo;
                split16(ar[bb], h, lo); Q[0]  = h; Q[8]  = lo;
                split16(ai[bb], h, lo); Q[16] = h; Q[24] = lo;
            }
        }
    }
}

// ---------------------------------------------------------------------------
// out[b][p][q][o] = Dq[(bl*8+o)][p*256+q] / 511^2 + bias[o]
// ---------------------------------------------------------------------------
__global__ __launch_bounds__(TPB)
void tout_k(const float* __restrict__ Dq, const float* __restrict__ bias,
            float* __restrict__ out, int b0)
{
    int idx = blockIdx.x * TPB + threadIdx.x;
    int o = idx & 7, q = (idx >> 3) & 255, p = (idx >> 11) & 255, bl = idx >> 19;
    float v = Dq[(size_t)(bl * 8 + o) * 65536 + p * 256 + q];
    out[(size_t)(b0 + bl) * 524288 + (size_t)(idx & 524287)] = v * (1.f / 261121.f) + bias[o];
}

// ---------------------------------------------------------------------------

extern "C" void kernel_launch(void* const* d_in, const int* in_sizes, int n_in,
                              void* d_out, int out_size, void* d_ws, size_t ws_size,
                              hipStream_t stream) {
    const float* x    = (const float*)d_in[0];
    const float* Kr   = (const float*)d_in[1];
    const float* Ki   = Kr + 16711744;          // 511*511*64
    const float* bias = (const float*)d_in[2];
    float* out = (float*)d_out;
    char* ws = (char*)d_ws;

    _Float16* AtabF = (_Float16*)(ws + 0);           //  1,048,576
    _Float16* CtabF = (_Float16*)(ws + 1048576);     //  1,048,576
    _Float16* Ct2F  = (_Float16*)(ws + 2097152);     //    524,288
    _Float16* xTp   = (_Float16*)(ws + 2621440);     // 16,777,216
    float*    KeR   = (float*)   (ws + 19398656);    // 33,554,432
    float*    KeI   = (float*)   (ws + 52953088);    // 33,554,432
    const size_t fixedEnd = 86507520;

    int g = 1;
    for (int cand = 8; cand >= 1; cand >>= 1) {
        if (fixedEnd + (size_t)cand * 16777216 <= ws_size) { g = cand; break; }
    }
    _Float16* F1  = (_Float16*)(ws + fixedEnd);                        // g*8 MB
    _Float16* F2T = (_Float16*)(ws + fixedEnd + (size_t)g * 8388608);  // g*8 MB
    _Float16* F1b = F1;                 // alias: F1 dead after S2
    float*    Dq  = (float*)F2T;        // alias: F2T dead after S4

    build_tables_k<<<160, TPB, 0, stream>>>(AtabF, CtabF, Ct2F);
    txp_k<<<dim3(8, 8, 8), TPB, 0, stream>>>(x, xTp);
    ksym_k<<<2048, TPB, 0, stream>>>(Kr, Ki, KeR, KeI);

    for (int b0 = 0; b0 < 8; b0 += g) {
        int Z = g * 8;
        // S1: F1[k1][w] (M=512,N=256,K=256), A=Atab, B=xTp (real)
        mgemm_k<2, true, false><<<dim3(2, 4, Z), TPB, 0, stream>>>(
            256, AtabF,
            xTp + (size_t)b0 * 8 * 131072, 131072,
            F1, 524288, 32, nullptr, 0, 0);

        // S2: F2T[k2][k1] (M=256,N=512,K=256), A=Atab(rows 0..255), B=F1
        mgemm_k<4, true, false><<<dim3(4, 2, Z), TPB, 0, stream>>>(
            256, AtabF,
            F1, 524288,
            F2T, 524288, 64, nullptr, 0, 0);

        // S3: channel mix
        einsum_k<<<512, TPB, 0, stream>>>(F2T, KeR, KeI, g);

        // S4: F1'[p][k2] (M=256,N=256,K=512), A=Ctab, B=F2T
        mgemm_k<4, true, false><<<dim3(2, 2, Z), TPB, 0, stream>>>(
            512, CtabF,
            F2T, 524288,
            F1b, 262144, 32, nullptr, 0, 0);

        // S5: Dq[p][q] (M=256,N=256,K=256), A=F1' (data), B=Ct2 table, fp32 Re
        mgemm_k<4, false, true><<<dim3(2, 2, Z), TPB, 0, stream>>>(
            256, Ct2F,
            F1b, 262144,
            nullptr, 0, 0, Dq, 65536, 256);

        // S6: transpose to NHWC + scale + bias
        tout_k<<<g * 2048, TPB, 0, stream>>>(Dq, bias, out, b0);
    }
}